// Round 2
// baseline (2908.867 us; speedup 1.0000x reference)
//
#include <hip/hip_runtime.h>
#include <math.h>

// B=256, T=256, D=80, H=512, 4H=2048, K=512
#define BB 256
#define TT 256
#define DDIM 80
#define HDIM 512
#define ROWSTRIDE 20480   // T*D

// ws layout (float offsets)
#define WS_CD    0          // 131072 (zeroed: dec cell state)
#define WS_HT0   131072     // 262144 (zeroed: tagged h ping, uint2 pairs)
#define WS_HT1   393216     // 262144 (zeroed: tagged h pong, uint2 pairs)
#define WS_QUANT 655360     // 131072
#define WS_VQP   786432     // 256
#define WS_BENC  786688     // 2048
#define WS_BDEC0 788736     // 2048
#define WS_BEFF  790784     // 2048
#define WS_WEFF  792832     // 2048*512 -> total 1841408 floats (7.4 MB)

typedef _Float16 f16;
typedef f16 half4_t __attribute__((ext_vector_type(4)));
typedef f16 half8_t __attribute__((ext_vector_type(8)));
typedef float float4_t __attribute__((ext_vector_type(4)));

__device__ __forceinline__ float sigmoidf_(float v) { return 1.0f / (1.0f + expf(-v)); }
__device__ __forceinline__ unsigned umin_(unsigned a, unsigned b) { return a < b ? a : b; }

// tagged 8B store: (f32 value, u32 generation) in one LLC-coherent dwordx2.
// 8B aligned single transaction -> tag and value become visible atomically.
__device__ __forceinline__ void llc_store_pair(uint2* p, float v, unsigned tag) {
  uint2 d; d.x = __float_as_uint(v); d.y = tag;
  asm volatile("global_store_dwordx2 %0, %1, off sc0 sc1" :: "v"(p), "v"(d) : "memory");
}

__global__ __launch_bounds__(256) void zero_kernel(float4* __restrict__ p, int n4) {
  int i = blockIdx.x * 256 + threadIdx.x;
  if (i < n4) p[i] = make_float4(0.f, 0.f, 0.f, 0.f);
}

__global__ __launch_bounds__(256) void bias_init_kernel(
    const float* __restrict__ eb1, const float* __restrict__ eb2,
    const float* __restrict__ db1, const float* __restrict__ db2,
    const float* __restrict__ dWih, const float* __restrict__ fcb,
    float* __restrict__ b_enc, float* __restrict__ b_dec0,
    float* __restrict__ b_eff) {
  int n = blockIdx.x * 256 + threadIdx.x;
  b_enc[n] = eb1[n] + eb2[n];
  float bd = db1[n] + db2[n];
  b_dec0[n] = bd;
  float acc = bd;
  #pragma unroll 16
  for (int d = 0; d < DDIM; d++) acc += dWih[n * DDIM + d] * fcb[d];
  b_eff[n] = acc;
}

// W_eff = dec_W_hh + dec_W_ih @ fc_W  (2048x512, K=80)
__global__ __launch_bounds__(256) void fold_kernel(
    const float* __restrict__ dWih, const float* __restrict__ dWhh,
    const float* __restrict__ fcW, float* __restrict__ W_eff) {
  int n = blockIdx.x;
  int tid = threadIdx.x;
  __shared__ float sw[DDIM];
  if (tid < DDIM) sw[tid] = dWih[n * DDIM + tid];
  __syncthreads();
  for (int k = tid; k < HDIM; k += 256) {
    float acc = dWhh[n * HDIM + k];
    #pragma unroll 16
    for (int d = 0; d < DDIM; d++) acc += sw[d] * fcW[d * HDIM + k];
    W_eff[n * HDIM + k] = acc;
  }
}

// ---------------- single LSTM step (decoder t=0 only; x = 0) ---------------------
// writes h_1 as tagged pairs (tag 257) so the persistent decoder's poll path
// accepts it with no special case.
__global__ __launch_bounds__(256) void lstm_step_kernel(
    const float* __restrict__ Whh, const float* __restrict__ bias,
    const float* __restrict__ h_in, float* __restrict__ c,
    uint2* __restrict__ h_out) {
  __shared__ float sh[16][516];
  int tid = threadIdx.x;
  int rt = blockIdx.x & 15, jt = blockIdx.x >> 4;
  int row0 = rt << 4;
  for (int i = tid; i < 2048; i += 256) {
    int r = i >> 7, kq = i & 127;
    float4 v = *(const float4*)(h_in + (size_t)(row0 + r) * HDIM + (kq << 2));
    *(float4*)&sh[r][kq << 2] = v;
  }
  __syncthreads();
  int r = tid & 15, j0 = tid >> 4;
  int j = (jt << 4) + j0;
  float a0 = bias[j], a1 = bias[512 + j], a2 = bias[1024 + j], a3 = bias[1536 + j];
  const float4* w0 = (const float4*)(Whh + (size_t)j * HDIM);
  const float4* w1 = (const float4*)(Whh + (size_t)(512 + j) * HDIM);
  const float4* w2 = (const float4*)(Whh + (size_t)(1024 + j) * HDIM);
  const float4* w3 = (const float4*)(Whh + (size_t)(1536 + j) * HDIM);
  const float4* hv = (const float4*)&sh[r][0];
  #pragma unroll 4
  for (int kq = 0; kq < 128; kq++) {
    float4 h4 = hv[kq];
    float4 q0 = w0[kq], q1 = w1[kq], q2 = w2[kq], q3 = w3[kq];
    a0 += h4.x * q0.x + h4.y * q0.y + h4.z * q0.z + h4.w * q0.w;
    a1 += h4.x * q1.x + h4.y * q1.y + h4.z * q1.z + h4.w * q1.w;
    a2 += h4.x * q2.x + h4.y * q2.y + h4.z * q2.z + h4.w * q2.w;
    a3 += h4.x * q3.x + h4.y * q3.y + h4.z * q3.z + h4.w * q3.w;
  }
  size_t idx = (size_t)(row0 + r) * HDIM + j;
  float cv = c[idx];
  float cn = sigmoidf_(a1) * cv + sigmoidf_(a0) * tanhf(a2);
  float hn = sigmoidf_(a3) * tanhf(cn);
  c[idx] = cn;
  uint2 o; o.x = __float_as_uint(hn); o.y = 257u;
  h_out[idx] = o;
}

// split one polled pair-quad into hi/lo f16 LDS rows.
// flat element e = 4*tid + 2048*kk (+0..3): row = (tid>>7)+4*kk, col = (tid&127)*4
#define SPLITP(LA, LB, kk) { \
    const int off_ = ((tid >> 7) + 4 * (kk)) * AST + (tid & 127) * 4; \
    const float f0_ = __uint_as_float(LA.x), f1_ = __uint_as_float(LA.z); \
    const float f2_ = __uint_as_float(LB.x), f3_ = __uint_as_float(LB.z); \
    half4_t hi4_, lo4_; \
    const f16 a_ = (f16)f0_, b2_ = (f16)f1_, c2_ = (f16)f2_, d_ = (f16)f3_; \
    hi4_[0] = a_; hi4_[1] = b2_; hi4_[2] = c2_; hi4_[3] = d_; \
    lo4_[0] = (f16)(f0_ - (float)a_);  lo4_[1] = (f16)(f1_ - (float)b2_); \
    lo4_[2] = (f16)(f2_ - (float)c2_); lo4_[3] = (f16)(f3_ - (float)d_); \
    *(half4_t*)&Ahi[off_] = hi4_; *(half4_t*)&Alo[off_] = lo4_; }

// Poll tagged h from LLC and stage into split-fp16 LDS.
// Base is offset to THIS BLOCK'S row slice (r0*HDIM pairs) — matches the
// producer-side hout[(r0+eb)*HDIM + d0+ed] indexing.
// Each thread's 32 pairs come from exactly ONE producer block (its dim quad
// lies inside one 16-dim slice), so threads drop out of the spin per-producer.
// Cheap 8B pre-gate spin first; then full 16x dwordx4 load with all-tags check.
#define POLL_STAGE(HIN, EXPT) { \
  const char* b_ = (const char*)((HIN) + (size_t)r0 * HDIM); \
  const int vo_ = tid * 32; \
  { \
    const uint2* g_ = (const uint2*)(b_ + vo_); \
    uint2 gv_; \
    for (;;) { \
      asm volatile("global_load_dwordx2 %0, %1, off sc0 sc1\n\ts_waitcnt vmcnt(0)" \
                   : "=&v"(gv_) : "v"(g_) : "memory"); \
      if (gv_.y >= (unsigned)(EXPT)) break; \
      __builtin_amdgcn_s_sleep(1); \
    } \
  } \
  uint4 A0,A1,A2,A3,A4,A5,A6,A7,A8,A9,A10,A11,A12,A13,A14,A15; \
  for (;;) { \
    asm volatile( \
      "global_load_dwordx4 %0, %16, %17 sc0 sc1\n\t" \
      "global_load_dwordx4 %1, %16, %17 offset:16 sc0 sc1\n\t" \
      "global_load_dwordx4 %2, %16, %18 sc0 sc1\n\t" \
      "global_load_dwordx4 %3, %16, %18 offset:16 sc0 sc1\n\t" \
      "global_load_dwordx4 %4, %16, %19 sc0 sc1\n\t" \
      "global_load_dwordx4 %5, %16, %19 offset:16 sc0 sc1\n\t" \
      "global_load_dwordx4 %6, %16, %20 sc0 sc1\n\t" \
      "global_load_dwordx4 %7, %16, %20 offset:16 sc0 sc1\n\t" \
      "global_load_dwordx4 %8, %16, %21 sc0 sc1\n\t" \
      "global_load_dwordx4 %9, %16, %21 offset:16 sc0 sc1\n\t" \
      "global_load_dwordx4 %10, %16, %22 sc0 sc1\n\t" \
      "global_load_dwordx4 %11, %16, %22 offset:16 sc0 sc1\n\t" \
      "global_load_dwordx4 %12, %16, %23 sc0 sc1\n\t" \
      "global_load_dwordx4 %13, %16, %23 offset:16 sc0 sc1\n\t" \
      "global_load_dwordx4 %14, %16, %24 sc0 sc1\n\t" \
      "global_load_dwordx4 %15, %16, %24 offset:16 sc0 sc1\n\t" \
      "s_waitcnt vmcnt(0)" \
      : "=&v"(A0), "=&v"(A1), "=&v"(A2), "=&v"(A3), \
        "=&v"(A4), "=&v"(A5), "=&v"(A6), "=&v"(A7), \
        "=&v"(A8), "=&v"(A9), "=&v"(A10), "=&v"(A11), \
        "=&v"(A12), "=&v"(A13), "=&v"(A14), "=&v"(A15) \
      : "v"(vo_), \
        "s"(b_), "s"(b_ + 16384), "s"(b_ + 32768), "s"(b_ + 49152), \
        "s"(b_ + 65536), "s"(b_ + 81920), "s"(b_ + 98304), "s"(b_ + 114688) \
      : "memory"); \
    unsigned m_ = umin_(umin_(A0.y, A0.w), umin_(A1.y, A1.w)); \
    m_ = umin_(m_, umin_(umin_(A2.y, A2.w), umin_(A3.y, A3.w))); \
    m_ = umin_(m_, umin_(umin_(A4.y, A4.w), umin_(A5.y, A5.w))); \
    m_ = umin_(m_, umin_(umin_(A6.y, A6.w), umin_(A7.y, A7.w))); \
    m_ = umin_(m_, umin_(umin_(A8.y, A8.w), umin_(A9.y, A9.w))); \
    m_ = umin_(m_, umin_(umin_(A10.y, A10.w), umin_(A11.y, A11.w))); \
    m_ = umin_(m_, umin_(umin_(A12.y, A12.w), umin_(A13.y, A13.w))); \
    m_ = umin_(m_, umin_(umin_(A14.y, A14.w), umin_(A15.y, A15.w))); \
    if (m_ >= (unsigned)(EXPT)) break; \
    __builtin_amdgcn_s_sleep(1); \
  } \
  SPLITP(A0, A1, 0); SPLITP(A2, A3, 1); SPLITP(A4, A5, 2); SPLITP(A6, A7, 3); \
  SPLITP(A8, A9, 4); SPLITP(A10, A11, 5); SPLITP(A12, A13, 6); SPLITP(A14, A15, 7); \
}

// ---------------- persistent MFMA LSTM (split-fp16, register-stationary W) -------
// 256 blocks (1/CU), 512 threads. Block (rt=bid&7, jt=bid>>3): rows [rt*32,+32),
// h-dims [jt*16,+16) -> 64 gate rows. Per step: h staged via tagged-pair poll
// (data IS the flag: no vmcnt drain, no flag store, no flag round trip);
// 4-term split-fp16 MFMA; elementwise; tagged h store. Ping-pong + full-group
// poll forms the cross-block barrier. Tags: enc 1..256, dec 257..512.
template <int IS_DEC>
__global__ __launch_bounds__(512, 2) void lstm_persist(
    const float* __restrict__ W,      // enc: eWhh; dec: W_eff  [2048][512]
    const float* __restrict__ Wih,    // enc only [2048][80]
    const float* __restrict__ bias,   // [2048]
    const float* __restrict__ traj,   // enc only
    const float* __restrict__ c_init, // dec: cD (holds c_1)
    const float* __restrict__ fcW, const float* __restrict__ fcb,
    float* __restrict__ recon,
    uint2* __restrict__ hT0, uint2* __restrict__ hT1) {
  constexpr int KT  = IS_DEC ? 16 : 19;    // k-tiles of 32 (enc: 512 h + 80 x + pad)
  constexpr int AST = IS_DEC ? 520 : 616;  // f16 row stride (16B aligned)
  __shared__ __align__(16) f16 Ahi[32 * AST];
  __shared__ __align__(16) f16 Alo[32 * AST];
  __shared__ float red[32 * 68];           // gates, stride 68
  __shared__ float ypart[IS_DEC ? 8 * 516 : 4];

  const int tid = threadIdx.x;
  const int bid = blockIdx.x;
  const int rt = bid & 7, jt = bid >> 3;
  const int r0 = rt * 32, d0 = jt * 16;
  const int wv = __builtin_amdgcn_readfirstlane(tid >> 6);
  const int l15 = tid & 15;
  const int q = (tid >> 4) & 3;            // quad within wave
  const int mt = wv >> 2, nt = wv & 3;     // nt = gate type

  // ---- register-stationary W: split-fp16 B-fragments ----
  const int grow = nt * 512 + d0 + l15;    // global gate row
  half8_t Whi[KT], Wlo[KT];
  #pragma unroll
  for (int kt = 0; kt < KT; kt++) {
    #pragma unroll
    for (int j = 0; j < 8; j++) {
      int k = kt * 32 + q * 8 + j;
      float w;
      if (k < 512) w = W[(size_t)grow * HDIM + k];
      else {
        int kx = k - 512;
        w = (!IS_DEC && kx < DDIM) ? Wih[(size_t)grow * DDIM + kx] : 0.f;
      }
      f16 hi = (f16)w;
      Whi[kt][j] = hi;
      Wlo[kt][j] = (f16)(w - (float)hi);
    }
  }
  const float breg = bias[grow];

  // dec: fcW fragments for fused y (jt<5 covers 80 dims; k-split by wave)
  half8_t Fhi[2], Flo[2];
  float ybias = 0.f;
  if (IS_DEC && jt < 5) {
    const int drow = jt * 16 + l15;
    #pragma unroll
    for (int kk = 0; kk < 2; kk++) {
      const int kt = wv * 2 + kk;
      #pragma unroll
      for (int j = 0; j < 8; j++) {
        float w = fcW[(size_t)drow * HDIM + kt * 32 + q * 8 + j];
        f16 hi = (f16)w;
        Fhi[kk][j] = hi;
        Flo[kk][j] = (f16)(w - (float)hi);
      }
    }
    ybias = fcb[jt * 16 + (tid & 15)];
  }

  const int eb = tid >> 4, ed = tid & 15;  // elementwise (row, dim)
  float c_reg = IS_DEC ? c_init[(size_t)(r0 + eb) * HDIM + d0 + ed] : 0.f;
  __syncthreads();

  const int t_begin = IS_DEC ? 1 : 0;
  for (int t = t_begin; t < TT; t++) {
    // ---- stage x tile first (enc; plain cached loads, independent of h) ----
    if (!IS_DEC) {  // cols 512..608, zeros past 592
      for (int i = tid; i < 768; i += 512) {
        int row = i / 24, c4 = i % 24;
        float4 v = (c4 < 20)
            ? *(const float4*)(traj + (size_t)(r0 + row) * ROWSTRIDE +
                               (size_t)t * DDIM + c4 * 4)
            : make_float4(0.f, 0.f, 0.f, 0.f);
        int off = row * AST + 512 + c4 * 4;
        half4_t hi4, lo4;
        float f0 = v.x, f1 = v.y, f2 = v.z, f3 = v.w;
        f16 a = (f16)f0, b = (f16)f1, cc = (f16)f2, d = (f16)f3;
        hi4[0] = a; hi4[1] = b; hi4[2] = cc; hi4[3] = d;
        lo4[0] = (f16)(f0 - (float)a); lo4[1] = (f16)(f1 - (float)b);
        lo4[2] = (f16)(f2 - (float)cc); lo4[3] = (f16)(f3 - (float)d);
        *(half4_t*)&Ahi[off] = hi4; *(half4_t*)&Alo[off] = lo4;
      }
    }
    // ---- stage h: t=0 enc is h0=0; else poll tagged pairs from LLC ----
    if (!IS_DEC && t == 0) {
      half4_t z4 = {(f16)0, (f16)0, (f16)0, (f16)0};
      #pragma unroll
      for (int k = 0; k < 8; k++) {
        int off = ((tid >> 7) + 4 * k) * AST + (tid & 127) * 4;
        *(half4_t*)&Ahi[off] = z4; *(half4_t*)&Alo[off] = z4;
      }
    } else {
      const uint2* hin = (t & 1) ? hT0 : hT1;
      const unsigned expt = IS_DEC ? (unsigned)(256 + t) : (unsigned)t;
      POLL_STAGE(hin, expt);
    }
    __syncthreads();

    // ---- gates: 4-term split-fp16 MFMA, full K per wave ----
    {
      float4_t acc0 = {breg, breg, breg, breg};
      float4_t acc1 = {0.f, 0.f, 0.f, 0.f};
      const int abase = (mt * 16 + l15) * AST + q * 8;
      #pragma unroll
      for (int kt = 0; kt < KT; kt++) {
        half8_t ahi = *(const half8_t*)&Ahi[abase + kt * 32];
        half8_t alo = *(const half8_t*)&Alo[abase + kt * 32];
        if (kt & 1) {
          acc1 = __builtin_amdgcn_mfma_f32_16x16x32_f16(ahi, Whi[kt], acc1, 0, 0, 0);
          acc1 = __builtin_amdgcn_mfma_f32_16x16x32_f16(alo, Whi[kt], acc1, 0, 0, 0);
          acc1 = __builtin_amdgcn_mfma_f32_16x16x32_f16(ahi, Wlo[kt], acc1, 0, 0, 0);
          acc1 = __builtin_amdgcn_mfma_f32_16x16x32_f16(alo, Wlo[kt], acc1, 0, 0, 0);
        } else {
          acc0 = __builtin_amdgcn_mfma_f32_16x16x32_f16(ahi, Whi[kt], acc0, 0, 0, 0);
          acc0 = __builtin_amdgcn_mfma_f32_16x16x32_f16(alo, Whi[kt], acc0, 0, 0, 0);
          acc0 = __builtin_amdgcn_mfma_f32_16x16x32_f16(ahi, Wlo[kt], acc0, 0, 0, 0);
          acc0 = __builtin_amdgcn_mfma_f32_16x16x32_f16(alo, Wlo[kt], acc0, 0, 0, 0);
        }
      }
      float4_t C = acc0 + acc1;
      #pragma unroll
      for (int i = 0; i < 4; i++)
        red[(mt * 16 + q * 4 + i) * 68 + nt * 16 + l15] = C[i];
    }
    // dec: fused y = fc(h_t) partials (k-split across waves)
    if (IS_DEC && jt < 5) {
      #pragma unroll
      for (int ym = 0; ym < 2; ym++) {
        float4_t ya = {0.f, 0.f, 0.f, 0.f};
        #pragma unroll
        for (int kk = 0; kk < 2; kk++) {
          const int kt = wv * 2 + kk;
          const int ao = (ym * 16 + l15) * AST + kt * 32 + q * 8;
          half8_t ahi = *(const half8_t*)&Ahi[ao];
          half8_t alo = *(const half8_t*)&Alo[ao];
          ya = __builtin_amdgcn_mfma_f32_16x16x32_f16(ahi, Fhi[kk], ya, 0, 0, 0);
          ya = __builtin_amdgcn_mfma_f32_16x16x32_f16(alo, Fhi[kk], ya, 0, 0, 0);
          ya = __builtin_amdgcn_mfma_f32_16x16x32_f16(ahi, Flo[kk], ya, 0, 0, 0);
          ya = __builtin_amdgcn_mfma_f32_16x16x32_f16(alo, Flo[kk], ya, 0, 0, 0);
        }
        #pragma unroll
        for (int i = 0; i < 4; i++)
          ypart[wv * 516 + (ym * 16 + q * 4 + i) * 16 + l15] = ya[i];
      }
    }
    __syncthreads();

    // ---- elementwise (c in VGPR); tagged h -> LLC (fire and forget) ----
    {
      float ig = red[eb * 68 + ed];
      float fg = red[eb * 68 + 16 + ed];
      float gg = red[eb * 68 + 32 + ed];
      float og = red[eb * 68 + 48 + ed];
      float cn = sigmoidf_(fg) * c_reg + sigmoidf_(ig) * tanhf(gg);
      c_reg = cn;
      float hn = sigmoidf_(og) * tanhf(cn);
      uint2* hout = (t & 1) ? hT1 : hT0;
      const unsigned ptag = IS_DEC ? (unsigned)(257 + t) : (unsigned)(t + 1);
      llc_store_pair(&hout[(size_t)(r0 + eb) * HDIM + d0 + ed], hn, ptag);
    }
    if (IS_DEC && jt < 5) {
      float acc = ybias;
      #pragma unroll
      for (int w8 = 0; w8 < 8; w8++) acc += ypart[w8 * 516 + tid];
      recon[(size_t)(r0 + (tid >> 4)) * ROWSTRIDE + (size_t)(t - 1) * DDIM +
            jt * 16 + (tid & 15)] = acc;
    }
    // no producer-side drain, no flag barrier: consumers poll the tags.
  }

  // ---- dec: recon col 255 = fc(h_256), polled from tagged hT1 (tag 512) ----
  if (IS_DEC) {
    if (jt >= 5) return;
    POLL_STAGE(hT1, 512u);
    __syncthreads();
    #pragma unroll
    for (int ym = 0; ym < 2; ym++) {
      float4_t ya = {0.f, 0.f, 0.f, 0.f};
      #pragma unroll
      for (int kk = 0; kk < 2; kk++) {
        const int kt = wv * 2 + kk;
        const int ao = (ym * 16 + l15) * AST + kt * 32 + q * 8;
        half8_t ahi = *(const half8_t*)&Ahi[ao];
        half8_t alo = *(const half8_t*)&Alo[ao];
        ya = __builtin_amdgcn_mfma_f32_16x16x32_f16(ahi, Fhi[kk], ya, 0, 0, 0);
        ya = __builtin_amdgcn_mfma_f32_16x16x32_f16(alo, Fhi[kk], ya, 0, 0, 0);
        ya = __builtin_amdgcn_mfma_f32_16x16x32_f16(ahi, Flo[kk], ya, 0, 0, 0);
        ya = __builtin_amdgcn_mfma_f32_16x16x32_f16(alo, Flo[kk], ya, 0, 0, 0);
      }
      #pragma unroll
      for (int i = 0; i < 4; i++)
        ypart[wv * 516 + (ym * 16 + q * 4 + i) * 16 + l15] = ya[i];
    }
    __syncthreads();
    {
      float acc = ybias;
      #pragma unroll
      for (int w8 = 0; w8 < 8; w8++) acc += ypart[w8 * 516 + tid];
      recon[(size_t)(r0 + (tid >> 4)) * ROWSTRIDE + (size_t)255 * DDIM +
            jt * 16 + (tid & 15)] = acc;
    }
  }
}

// ---------------- vector quantizer (z read from tagged pairs) --------------------
__global__ __launch_bounds__(256) void vq_kernel(
    const uint2* __restrict__ zt, const float* __restrict__ emb,
    float* __restrict__ quant, float* __restrict__ vq_part,
    float* __restrict__ out_idx) {
  __shared__ float sz[512];
  __shared__ float sd[256];
  __shared__ int si[256];
  int b = blockIdx.x, tid = threadIdx.x;
  sz[tid] = __uint_as_float(zt[(size_t)b * HDIM + tid].x);
  sz[tid + 256] = __uint_as_float(zt[(size_t)b * HDIM + 256 + tid].x);
  __syncthreads();
  float bd = 3.4e38f;
  int bk = 0;
  for (int k = tid; k < 512; k += 256) {
    const float4* e4 = (const float4*)(emb + (size_t)k * HDIM);
    const float4* z4 = (const float4*)sz;
    float dot = 0.f, ee = 0.f;
    #pragma unroll 4
    for (int qq = 0; qq < 128; qq++) {
      float4 ev = e4[qq], zv = z4[qq];
      dot += ev.x * zv.x + ev.y * zv.y + ev.z * zv.z + ev.w * zv.w;
      ee += ev.x * ev.x + ev.y * ev.y + ev.z * ev.z + ev.w * ev.w;
    }
    float dist = ee - 2.f * dot;
    if (dist < bd) { bd = dist; bk = k; }
  }
  sd[tid] = bd; si[tid] = bk;
  __syncthreads();
  for (int s = 128; s > 0; s >>= 1) {
    if (tid < s) {
      float od = sd[tid + s]; int ok = si[tid + s];
      if (od < sd[tid] || (od == sd[tid] && ok < si[tid])) { sd[tid] = od; si[tid] = ok; }
    }
    __syncthreads();
  }
  int kbest = si[0];
  __syncthreads();
  float e0 = emb[(size_t)kbest * HDIM + tid];
  float e1 = emb[(size_t)kbest * HDIM + 256 + tid];
  quant[(size_t)b * HDIM + tid] = e0;
  quant[(size_t)b * HDIM + 256 + tid] = e1;
  float q0 = e0 - sz[tid], q1 = e1 - sz[tid + 256];
  sd[tid] = q0 * q0 + q1 * q1;
  __syncthreads();
  for (int st = 128; st > 0; st >>= 1) {
    if (tid < st) sd[tid] += sd[tid + st];
    __syncthreads();
  }
  if (tid == 0) { vq_part[b] = sd[0]; out_idx[b] = (float)kbest; }
}

__global__ __launch_bounds__(256) void vq_reduce_kernel(const float* __restrict__ vq_part,
                                                        float* __restrict__ out_loss) {
  __shared__ float s[256];
  int tid = threadIdx.x;
  s[tid] = vq_part[tid];
  __syncthreads();
  for (int st = 128; st > 0; st >>= 1) {
    if (tid < st) s[tid] += s[tid + st];
    __syncthreads();
  }
  if (tid == 0) out_loss[0] = s[0] * 1.25f / (float)(BB * HDIM);
}

extern "C" void kernel_launch(void* const* d_in, const int* in_sizes, int n_in,
                              void* d_out, int out_size, void* d_ws, size_t ws_size,
                              hipStream_t stream) {
  const float* traj = (const float*)d_in[0];
  const float* eWih = (const float*)d_in[2];
  const float* eWhh = (const float*)d_in[3];
  const float* eb1  = (const float*)d_in[4];
  const float* eb2  = (const float*)d_in[5];
  const float* emb  = (const float*)d_in[6];
  const float* dWih = (const float*)d_in[7];
  const float* dWhh = (const float*)d_in[8];
  const float* db1  = (const float*)d_in[9];
  const float* db2  = (const float*)d_in[10];
  const float* fcW  = (const float*)d_in[11];
  const float* fcb  = (const float*)d_in[12];

  float* out = (float*)d_out;
  float* recon = out;
  float* out_loss = out + 5242880;
  float* out_idx = out + 5242881;

  float* ws = (float*)d_ws;
  float* cD      = ws + WS_CD;
  uint2* hT0     = (uint2*)(ws + WS_HT0);
  uint2* hT1     = (uint2*)(ws + WS_HT1);
  float* quant   = ws + WS_QUANT;
  float* vq_part = ws + WS_VQP;
  float* b_enc   = ws + WS_BENC;
  float* b_dec0  = ws + WS_BDEC0;
  float* b_eff   = ws + WS_BEFF;
  float* W_eff   = ws + WS_WEFF;

  // zero cD + tagged ping-pong buffers (tags must start < 1 each launch)
  zero_kernel<<<640, 256, 0, stream>>>((float4*)ws, 163840);
  bias_init_kernel<<<8, 256, 0, stream>>>(eb1, eb2, db1, db2, dWih, fcb,
                                          b_enc, b_dec0, b_eff);
  fold_kernel<<<2048, 256, 0, stream>>>(dWih, dWhh, fcW, W_eff);

  // encoder: t=0..255 persistent; z lands tagged in hT1 (tag 256)
  lstm_persist<0><<<256, 512, 0, stream>>>(
      eWhh, eWih, b_enc, traj, nullptr, nullptr, nullptr, nullptr, hT0, hT1);

  vq_kernel<<<256, 256, 0, stream>>>(hT1, emb, quant, vq_part, out_idx);
  vq_reduce_kernel<<<1, 256, 0, stream>>>(vq_part, out_loss);

  // decoder t=0 (plain dWhh, x=0): h_1 -> hT0 (tag 257), c_1 -> cD
  lstm_step_kernel<<<512, 256, 0, stream>>>(dWhh, b_dec0, quant, cD, hT0);
  // decoder t=1..255 persistent with W_eff; recon fused
  lstm_persist<1><<<256, 512, 0, stream>>>(
      W_eff, nullptr, b_eff, nullptr, cD, fcW, fcb, recon, hT0, hT1);
}